// Round 16
// baseline (320.820 us; speedup 1.0000x reference)
//
#include <hip/hip_runtime.h>
#include <hip/hip_bf16.h>
#include <stdint.h>

#define NROWS   65536
#define EPS     1e-5f
#define BM      32
#define NBLK    (NROWS / BM)   // 2048

typedef __attribute__((ext_vector_type(8))) short short8;
typedef __attribute__((ext_vector_type(4))) float f32x4;

__device__ __forceinline__ unsigned short f2bf(float f) {
    unsigned u = __float_as_uint(f);
    unsigned r = (u + 0x7FFFu + ((u >> 16) & 1u)) >> 16;
    return (unsigned short)r;
}

// one-instruction packed fp32x2 -> bf16x2 (RNE), gfx950
__device__ __forceinline__ unsigned cvtpk(float lo, float hi) {
    unsigned r;
    asm("v_cvt_pk_bf16_f32 %0, %1, %2" : "=v"(r) : "v"(lo), "v"(hi));
    return r;
}

// LDS cell addressing: k-packed cells of 8 bf16 (16 B), cell(kg, r) for 32 rows,
// XOR-swizzled (proven R4-R15; writer+reader agree).
__device__ __forceinline__ int cellb(int kg, int r) {
    return (((kg << 5) + r) << 4) ^ ((kg & 3) << 5);
}

__device__ __forceinline__ uint4 pack8(float4 a0, float4 a1, float4 b0, float4 b1) {
    uint4 pk;
    pk.x = cvtpk(a0.x + b0.x, a0.y + b0.y);
    pk.y = cvtpk(a0.z + b0.z, a0.w + b0.w);
    pk.z = cvtpk(a1.x + b1.x, a1.y + b1.y);
    pk.w = cvtpk(a1.z + b1.z, a1.w + b1.w);
    return pk;
}

// ---------------- K0: weights -> bf16, MFMA-fragment-packed (16x16) ----------------
__global__ void k_prep(const float* __restrict__ W1, const float* __restrict__ W2,
                       const float* __restrict__ W3,
                       unsigned short* __restrict__ w1p, unsigned short* __restrict__ w2p,
                       unsigned short* __restrict__ w3p) {
    int idx = blockIdx.x * 256 + threadIdx.x;
    if (idx < 131072) {                      // W1: K=256 (kt 0..7), N=512 (tile 0..31)
        int j = idx & 7, l = (idx >> 3) & 63, kt = (idx >> 9) & 7, tile = idx >> 12;
        int n = tile * 16 + (l & 15);
        int k = kt * 32 + (l >> 4) * 8 + j;
        w1p[idx] = f2bf(W1[k * 512 + n]);
    } else if (idx < 393216) {               // W2: K=512 (kt 0..15), N=512 (tile 0..31)
        int i2 = idx - 131072;
        int j = i2 & 7, l = (i2 >> 3) & 63, kt = (i2 >> 9) & 15, tile = i2 >> 13;
        int n = tile * 16 + (l & 15);
        int k = kt * 32 + (l >> 4) * 8 + j;
        w2p[i2] = f2bf(W2[k * 512 + n]);
    } else if (idx < 524288) {               // W3: K=512 (kt 0..15), N=256 (tile 0..15)
        int i3 = idx - 393216;
        int j = i3 & 7, l = (i3 >> 3) & 63, kt = (i3 >> 9) & 15, tile = i3 >> 13;
        int n = tile * 16 + (l & 15);
        int k = kt * 32 + (l >> 4) * 8 + j;
        w3p[i3] = f2bf(W3[k * 256 + n]);
    }
}

// ---------------- K1: fused MLP chain — EDGE-INNER + depth-2 B prefetch (R16) ----------------
// 2048 blocks x 512 thr (8 waves), block owns 32 batch rows.
// B-fragments: 3-slot rotation, slot kt%3, reload slot<-kt+3 after use ->
// ~2 phases (>=232 cyc) of L2-latency cover (depth-1 gave only ~116).
// A-fragments: 2-slot ping-pong (kt%2), reload slot<-kt+2 after use (LDS ~120cyc).
// All buffer indices are LITERAL (macro-expanded phases) — rule #20.
// Regs ~220 <= 256 cap; occupancy LDS-bound (144KB -> 1 blk/CU) so regs free.
// amdgpu_waves_per_eu(2,2) pins the allocator (R12 lesson).
__global__ __launch_bounds__(512) __attribute__((amdgpu_waves_per_eu(2, 2)))
void k_fused(const float* __restrict__ x,
             const unsigned short* __restrict__ w1p,
             const unsigned short* __restrict__ w2p,
             const unsigned short* __restrict__ w3p,
             const float* __restrict__ b1, const float* __restrict__ b2,
             const float* __restrict__ b3,
             float* __restrict__ out,
             float* __restrict__ psum, float* __restrict__ psumsq) {
    __shared__ __align__(16) unsigned char smem[147456];
    unsigned char* h1b  = smem;             // 3 x 32 KB
    unsigned char* ebb  = smem + 98304;     // 3 x 16 KB
    unsigned char* aggb = smem + 98304;     // 32 KB (aliases ebuf0+ebuf1)
    float* zbuf = (float*)smem;             // 32 KB (aliases h1s[0])

    const int tid = threadIdx.x;
    const int w   = tid >> 6;
    const int l   = tid & 63;
    const int l15 = l & 15;
    const int lg  = l >> 4;
    const int blk = blockIdx.x;
    const int row0 = blk * BM;

    const int sr  = tid & 31;
    const int skg = tid >> 5;
    const float* xrow = x + (size_t)(row0 + sr) * 768;

    float bias1[4], bias2[4];
#pragma unroll
    for (int nt = 0; nt < 4; ++nt) {
        bias1[nt] = b1[w * 64 + nt * 16 + l15];
        bias2[nt] = b2[w * 64 + nt * 16 + l15];
    }
    float bias3[2];
#pragma unroll
    for (int nt = 0; nt < 2; ++nt) bias3[nt] = b3[w * 32 + nt * 16 + l15];

    // ---- stage all 3 edge buffers (x loaded once per node) ----
#pragma unroll
    for (int h = 0; h < 2; ++h) {
        int kg = skg + h * 16;
        float4 n0a = *(const float4*)(xrow + kg * 8);
        float4 n0b = *(const float4*)(xrow + kg * 8 + 4);
        float4 n1a = *(const float4*)(xrow + 256 + kg * 8);
        float4 n1b = *(const float4*)(xrow + 256 + kg * 8 + 4);
        float4 n2a = *(const float4*)(xrow + 512 + kg * 8);
        float4 n2b = *(const float4*)(xrow + 512 + kg * 8 + 4);
        *(uint4*)(ebb + cellb(kg, sr))         = pack8(n0a, n0b, n1a, n1b);  // e01
        *(uint4*)(ebb + 16384 + cellb(kg, sr)) = pack8(n0a, n0b, n2a, n2b);  // e02
        *(uint4*)(ebb + 32768 + cellb(kg, sr)) = pack8(n1a, n1b, n2a, n2b);  // e12
    }

    // ================= layer1: c1[e] = e @ W1 (K=256, 8 kt) =================
    f32x4 c1[3][2][4];
#pragma unroll
    for (int e = 0; e < 3; ++e)
#pragma unroll
        for (int mt = 0; mt < 2; ++mt)
#pragma unroll
            for (int nt = 0; nt < 4; ++nt) c1[e][mt][nt] = (f32x4){0.f, 0.f, 0.f, 0.f};

    {
        short8 a1f[2][3][2], b1f[3][4];

#define L1_LA(S_, K_) do { \
        a1f[S_][0][0] = *(const short8*)(ebb +     0 + cellb((K_) * 4 + lg,      l15)); \
        a1f[S_][0][1] = *(const short8*)(ebb +     0 + cellb((K_) * 4 + lg, 16 + l15)); \
        a1f[S_][1][0] = *(const short8*)(ebb + 16384 + cellb((K_) * 4 + lg,      l15)); \
        a1f[S_][1][1] = *(const short8*)(ebb + 16384 + cellb((K_) * 4 + lg, 16 + l15)); \
        a1f[S_][2][0] = *(const short8*)(ebb + 32768 + cellb((K_) * 4 + lg,      l15)); \
        a1f[S_][2][1] = *(const short8*)(ebb + 32768 + cellb((K_) * 4 + lg, 16 + l15)); \
    } while (0)

#define L1_LB(S_, K_) do { \
        b1f[S_][0] = *(const short8*)(w1p + (((w * 4 + 0) * 8 + (K_)) * 64 + l) * 8); \
        b1f[S_][1] = *(const short8*)(w1p + (((w * 4 + 1) * 8 + (K_)) * 64 + l) * 8); \
        b1f[S_][2] = *(const short8*)(w1p + (((w * 4 + 2) * 8 + (K_)) * 64 + l) * 8); \
        b1f[S_][3] = *(const short8*)(w1p + (((w * 4 + 3) * 8 + (K_)) * 64 + l) * 8); \
    } while (0)

#define L1_PHASE(K_) do { \
        __builtin_amdgcn_s_setprio(1); \
        _Pragma("unroll") \
        for (int nt = 0; nt < 4; ++nt) \
            _Pragma("unroll") \
            for (int e = 0; e < 3; ++e) \
                _Pragma("unroll") \
                for (int mt = 0; mt < 2; ++mt) \
                    c1[e][mt][nt] = __builtin_amdgcn_mfma_f32_16x16x32_bf16( \
                        a1f[(K_) % 2][e][mt], b1f[(K_) % 3][nt], c1[e][mt][nt], 0, 0, 0); \
        __builtin_amdgcn_s_setprio(0); \
        if ((K_) + 2 < 8) L1_LA((K_) % 2, (K_) + 2); \
        if ((K_) + 3 < 8) L1_LB((K_) % 3, (K_) + 3); \
    } while (0)

        // B prologue pre-barrier (hides L2 latency under barrier drain)
        L1_LB(0, 0); L1_LB(1, 1); L1_LB(2, 2);
        __syncthreads();   // ebuf ready
        L1_LA(0, 0); L1_LA(1, 1);
        L1_PHASE(0); L1_PHASE(1); L1_PHASE(2); L1_PHASE(3);
        L1_PHASE(4); L1_PHASE(5); L1_PHASE(6); L1_PHASE(7);
    }

    // ---- layer1 epilogue: relu(c1+b1) -> h1s[e] (cvt_pk pairs, u16 lo/hi stores) ----
#pragma unroll
    for (int e = 0; e < 3; ++e)
#pragma unroll
        for (int nt = 0; nt < 4; ++nt) {
            int c = w * 64 + nt * 16 + l15;
            int cb = ((c & 7) << 1);
            unsigned char* base = h1b + e * 32768;
#pragma unroll
            for (int mt = 0; mt < 2; ++mt) {
                int r0 = mt * 16 + lg * 4;
                float v0 = fmaxf(c1[e][mt][nt][0] + bias1[nt], 0.f);
                float v1 = fmaxf(c1[e][mt][nt][1] + bias1[nt], 0.f);
                float v2 = fmaxf(c1[e][mt][nt][2] + bias1[nt], 0.f);
                float v3 = fmaxf(c1[e][mt][nt][3] + bias1[nt], 0.f);
                unsigned p01 = cvtpk(v0, v1);
                unsigned p23 = cvtpk(v2, v3);
                *(unsigned short*)(base + cellb(c >> 3, r0 + 0) + cb) = (unsigned short)p01;
                *(unsigned short*)(base + cellb(c >> 3, r0 + 1) + cb) = (unsigned short)(p01 >> 16);
                *(unsigned short*)(base + cellb(c >> 3, r0 + 2) + cb) = (unsigned short)p23;
                *(unsigned short*)(base + cellb(c >> 3, r0 + 3) + cb) = (unsigned short)(p23 >> 16);
            }
        }

    // ================= layer2: c2[e] = h1[e] @ W2 (K=512, 16 kt) =================
    f32x4 c2[3][2][4];
#pragma unroll
    for (int e = 0; e < 3; ++e)
#pragma unroll
        for (int mt = 0; mt < 2; ++mt)
#pragma unroll
            for (int nt = 0; nt < 4; ++nt) c2[e][mt][nt] = (f32x4){0.f, 0.f, 0.f, 0.f};

    {
        short8 a2f[2][3][2], b2f[3][4];

#define L2_LA(S_, K_) do { \
        a2f[S_][0][0] = *(const short8*)(h1b +     0 + cellb((K_) * 4 + lg,      l15)); \
        a2f[S_][0][1] = *(const short8*)(h1b +     0 + cellb((K_) * 4 + lg, 16 + l15)); \
        a2f[S_][1][0] = *(const short8*)(h1b + 32768 + cellb((K_) * 4 + lg,      l15)); \
        a2f[S_][1][1] = *(const short8*)(h1b + 32768 + cellb((K_) * 4 + lg, 16 + l15)); \
        a2f[S_][2][0] = *(const short8*)(h1b + 65536 + cellb((K_) * 4 + lg,      l15)); \
        a2f[S_][2][1] = *(const short8*)(h1b + 65536 + cellb((K_) * 4 + lg, 16 + l15)); \
    } while (0)

#define L2_LB(S_, K_) do { \
        b2f[S_][0] = *(const short8*)(w2p + (((w * 4 + 0) * 16 + (K_)) * 64 + l) * 8); \
        b2f[S_][1] = *(const short8*)(w2p + (((w * 4 + 1) * 16 + (K_)) * 64 + l) * 8); \
        b2f[S_][2] = *(const short8*)(w2p + (((w * 4 + 2) * 16 + (K_)) * 64 + l) * 8); \
        b2f[S_][3] = *(const short8*)(w2p + (((w * 4 + 3) * 16 + (K_)) * 64 + l) * 8); \
    } while (0)

#define L2_PHASE(K_) do { \
        __builtin_amdgcn_s_setprio(1); \
        _Pragma("unroll") \
        for (int nt = 0; nt < 4; ++nt) \
            _Pragma("unroll") \
            for (int e = 0; e < 3; ++e) \
                _Pragma("unroll") \
                for (int mt = 0; mt < 2; ++mt) \
                    c2[e][mt][nt] = __builtin_amdgcn_mfma_f32_16x16x32_bf16( \
                        a2f[(K_) % 2][e][mt], b2f[(K_) % 3][nt], c2[e][mt][nt], 0, 0, 0); \
        __builtin_amdgcn_s_setprio(0); \
        if ((K_) + 2 < 16) L2_LA((K_) % 2, (K_) + 2); \
        if ((K_) + 3 < 16) L2_LB((K_) % 3, (K_) + 3); \
    } while (0)

        // B prologue pre-barrier
        L2_LB(0, 0); L2_LB(1, 1); L2_LB(2, 2);
        __syncthreads();   // h1s ready; ebuf reads done (aggb overwrite safe later)
        L2_LA(0, 0); L2_LA(1, 1);
        L2_PHASE(0);  L2_PHASE(1);  L2_PHASE(2);  L2_PHASE(3);
        L2_PHASE(4);  L2_PHASE(5);  L2_PHASE(6);  L2_PHASE(7);
        L2_PHASE(8);  L2_PHASE(9);  L2_PHASE(10); L2_PHASE(11);
        L2_PHASE(12); L2_PHASE(13); L2_PHASE(14); L2_PHASE(15);
    }

    // ---- agg = sum_e relu(c2[e]+b2) -> aggb (cvt_pk pairs, u16 lo/hi stores) ----
#pragma unroll
    for (int nt = 0; nt < 4; ++nt) {
        int c = w * 64 + nt * 16 + l15;
        int cb = ((c & 7) << 1);
#pragma unroll
        for (int mt = 0; mt < 2; ++mt) {
            int r0 = mt * 16 + lg * 4;
            float s0 = 0.f, s1 = 0.f, s2 = 0.f, s3 = 0.f;
#pragma unroll
            for (int e = 0; e < 3; ++e) {
                s0 += fmaxf(c2[e][mt][nt][0] + bias2[nt], 0.f);
                s1 += fmaxf(c2[e][mt][nt][1] + bias2[nt], 0.f);
                s2 += fmaxf(c2[e][mt][nt][2] + bias2[nt], 0.f);
                s3 += fmaxf(c2[e][mt][nt][3] + bias2[nt], 0.f);
            }
            unsigned p01 = cvtpk(s0, s1);
            unsigned p23 = cvtpk(s2, s3);
            *(unsigned short*)(aggb + cellb(c >> 3, r0 + 0) + cb) = (unsigned short)p01;
            *(unsigned short*)(aggb + cellb(c >> 3, r0 + 1) + cb) = (unsigned short)(p01 >> 16);
            *(unsigned short*)(aggb + cellb(c >> 3, r0 + 2) + cb) = (unsigned short)p23;
            *(unsigned short*)(aggb + cellb(c >> 3, r0 + 3) + cb) = (unsigned short)(p23 >> 16);
        }
    }

    // ================= layer3: z = agg @ W3 + b3 (K=512, 16 kt) =================
    f32x4 c3[2][2];
#pragma unroll
    for (int mt = 0; mt < 2; ++mt)
#pragma unroll
        for (int nt = 0; nt < 2; ++nt) c3[mt][nt] = (f32x4){0.f, 0.f, 0.f, 0.f};

    {
        short8 a3f[2][2], b3f[3][2];

#define L3_LA(S_, K_) do { \
        a3f[S_][0] = *(const short8*)(aggb + cellb((K_) * 4 + lg,      l15)); \
        a3f[S_][1] = *(const short8*)(aggb + cellb((K_) * 4 + lg, 16 + l15)); \
    } while (0)

#define L3_LB(S_, K_) do { \
        b3f[S_][0] = *(const short8*)(w3p + (((w * 2 + 0) * 16 + (K_)) * 64 + l) * 8); \
        b3f[S_][1] = *(const short8*)(w3p + (((w * 2 + 1) * 16 + (K_)) * 64 + l) * 8); \
    } while (0)

#define L3_PHASE(K_) do { \
        __builtin_amdgcn_s_setprio(1); \
        _Pragma("unroll") \
        for (int nt = 0; nt < 2; ++nt) \
            _Pragma("unroll") \
            for (int mt = 0; mt < 2; ++mt) \
                c3[mt][nt] = __builtin_amdgcn_mfma_f32_16x16x32_bf16( \
                    a3f[(K_) % 2][mt], b3f[(K_) % 3][nt], c3[mt][nt], 0, 0, 0); \
        __builtin_amdgcn_s_setprio(0); \
        if ((K_) + 2 < 16) L3_LA((K_) % 2, (K_) + 2); \
        if ((K_) + 3 < 16) L3_LB((K_) % 3, (K_) + 3); \
    } while (0)

        // B prologue pre-barrier
        L3_LB(0, 0); L3_LB(1, 1); L3_LB(2, 2);
        __syncthreads();   // aggb complete; h1s reads all done
        L3_LA(0, 0); L3_LA(1, 1);
        L3_PHASE(0);  L3_PHASE(1);  L3_PHASE(2);  L3_PHASE(3);
        L3_PHASE(4);  L3_PHASE(5);  L3_PHASE(6);  L3_PHASE(7);
        L3_PHASE(8);  L3_PHASE(9);  L3_PHASE(10); L3_PHASE(11);
        L3_PHASE(12); L3_PHASE(13); L3_PHASE(14); L3_PHASE(15);
    }

    // ---- z epilogue: zbuf (h1s[0] region — disjoint from aggb) + BN partials ----
#pragma unroll
    for (int nt = 0; nt < 2; ++nt) {
        int c = w * 32 + nt * 16 + l15;
        float s = 0.f, q = 0.f;
#pragma unroll
        for (int mt = 0; mt < 2; ++mt)
#pragma unroll
            for (int reg = 0; reg < 4; ++reg) {
                int r = mt * 16 + lg * 4 + reg;
                float v = c3[mt][nt][reg] + bias3[nt];
                zbuf[r * 256 + c] = v;
                s += v;
                q += v * v;
            }
        s += __shfl_xor(s, 16); s += __shfl_xor(s, 32);
        q += __shfl_xor(q, 16); q += __shfl_xor(q, 32);
        if (lg == 0) {
            psum[c * NBLK + blk] = s;
            psumsq[c * NBLK + blk] = q;
        }
    }
    __syncthreads();
    {
        const float4* zb4 = (const float4*)zbuf;
        float4* o4 = (float4*)(out + (size_t)row0 * 256);
#pragma unroll
        for (int i = 0; i < 4; ++i)
            o4[tid + i * 512] = zb4[tid + i * 512];
    }
}

// ---------------- K2: reduce 2048 partials -> scale/shift ----------------
__global__ void k_stats2(const float* __restrict__ psum, const float* __restrict__ psumsq,
                         const float* __restrict__ gamma, const float* __restrict__ beta,
                         float* __restrict__ scale, float* __restrict__ shift) {
    int f = blockIdx.x, t = threadIdx.x;
    const float* ps = psum + f * NBLK;
    const float* pq = psumsq + f * NBLK;
    float s = 0.f, q = 0.f;
#pragma unroll
    for (int i = 0; i < 8; ++i) {
        s += ps[t + i * 256];
        q += pq[t + i * 256];
    }
#pragma unroll
    for (int o = 32; o > 0; o >>= 1) {
        s += __shfl_down(s, o);
        q += __shfl_down(q, o);
    }
    __shared__ float ls[4], lq[4];
    if ((t & 63) == 0) { ls[t >> 6] = s; lq[t >> 6] = q; }
    __syncthreads();
    if (t == 0) {
        s = ls[0] + ls[1] + ls[2] + ls[3];
        q = lq[0] + lq[1] + lq[2] + lq[3];
        float mu  = s * (1.f / 65536.f);
        float var = q * (1.f / 65536.f) - mu * mu;
        float sc  = gamma[f] * rsqrtf(var + EPS);
        scale[f] = sc;
        shift[f] = beta[f] - mu * sc;
    }
}

// ---------------- K3: in-place normalize of d_out ----------------
__global__ void k_norm(float4* __restrict__ out4, const float4* __restrict__ scale4,
                       const float4* __restrict__ shift4, int n4) {
    int i = blockIdx.x * blockDim.x + threadIdx.x;
    int stride = gridDim.x * blockDim.x;
    for (; i < n4; i += stride) {
        float4 v = out4[i];
        float4 sc = scale4[i & 63];
        float4 sh = shift4[i & 63];
        v.x = v.x * sc.x + sh.x;
        v.y = v.y * sc.y + sh.y;
        v.z = v.z * sc.z + sh.z;
        v.w = v.w * sc.w + sh.w;
        out4[i] = v;
    }
}

extern "C" void kernel_launch(void* const* d_in, const int* in_sizes, int n_in,
                              void* d_out, int out_size, void* d_ws, size_t ws_size,
                              hipStream_t stream) {
    const float* x     = (const float*)d_in[0];
    const float* W1    = (const float*)d_in[1];
    const float* b1    = (const float*)d_in[2];
    const float* W2    = (const float*)d_in[3];
    const float* b2    = (const float*)d_in[4];
    const float* W3    = (const float*)d_in[5];
    const float* b3    = (const float*)d_in[6];
    const float* gamma = (const float*)d_in[7];
    const float* beta  = (const float*)d_in[8];

    char* ws = (char*)d_ws;
    unsigned short* w1p = (unsigned short*)(ws);            // 256 KB
    unsigned short* w2p = (unsigned short*)(ws + 262144);   // 512 KB
    unsigned short* w3p = (unsigned short*)(ws + 786432);   // 256 KB
    float* psum   = (float*)(ws + 1048576);                 // 2 MB
    float* psumsq = (float*)(ws + 3145728);                 // 2 MB
    float* scale  = (float*)(ws + 5242880);                 // 1 KB
    float* shift  = (float*)(ws + 5243904);                 // 1 KB

    float* out = (float*)d_out;

    k_prep<<<2048, 256, 0, stream>>>(W1, W2, W3, w1p, w2p, w3p);
    k_fused<<<NBLK, 512, 0, stream>>>(x, w1p, w2p, w3p, b1, b2, b3, out, psum, psumsq);
    k_stats2<<<256, 256, 0, stream>>>(psum, psumsq, gamma, beta, scale, shift);
    k_norm<<<2048, 256, 0, stream>>>((float4*)out, (const float4*)scale, (const float4*)shift,
                                     (NROWS * 256) / 4);
}

// Round 17
// 225.606 us; speedup vs baseline: 1.4220x; 1.4220x over previous
//
#include <hip/hip_runtime.h>
#include <hip/hip_bf16.h>
#include <stdint.h>

#define NROWS   65536
#define EPS     1e-5f
#define BM      32
#define NBLK    (NROWS / BM)   // 2048

typedef __attribute__((ext_vector_type(8))) short short8;
typedef __attribute__((ext_vector_type(4))) float f32x4;

__device__ __forceinline__ unsigned short f2bf(float f) {
    unsigned u = __float_as_uint(f);
    unsigned r = (u + 0x7FFFu + ((u >> 16) & 1u)) >> 16;
    return (unsigned short)r;
}

// one-instruction packed fp32x2 -> bf16x2 (RNE), gfx950
__device__ __forceinline__ unsigned cvtpk(float lo, float hi) {
    unsigned r;
    asm("v_cvt_pk_bf16_f32 %0, %1, %2" : "=v"(r) : "v"(lo), "v"(hi));
    return r;
}

__device__ __forceinline__ float bf2f(unsigned short v) {
    return __uint_as_float(((unsigned)v) << 16);
}

// LDS cell addressing: k-packed cells of 8 bf16 (16 B), cell(kg, r) for 32 rows,
// XOR-swizzled (proven R4-R15; writer+reader agree).
__device__ __forceinline__ int cellb(int kg, int r) {
    return (((kg << 5) + r) << 4) ^ ((kg & 3) << 5);
}

__device__ __forceinline__ uint4 pack8(float4 a0, float4 a1, float4 b0, float4 b1) {
    uint4 pk;
    pk.x = cvtpk(a0.x + b0.x, a0.y + b0.y);
    pk.y = cvtpk(a0.z + b0.z, a0.w + b0.w);
    pk.z = cvtpk(a1.x + b1.x, a1.y + b1.y);
    pk.w = cvtpk(a1.z + b1.z, a1.w + b1.w);
    return pk;
}

// ---------------- K0: weights -> bf16, MFMA-fragment-packed (16x16) ----------------
__global__ void k_prep(const float* __restrict__ W1, const float* __restrict__ W2,
                       const float* __restrict__ W3,
                       unsigned short* __restrict__ w1p, unsigned short* __restrict__ w2p,
                       unsigned short* __restrict__ w3p) {
    int idx = blockIdx.x * 256 + threadIdx.x;
    if (idx < 131072) {                      // W1: K=256 (kt 0..7), N=512 (tile 0..31)
        int j = idx & 7, l = (idx >> 3) & 63, kt = (idx >> 9) & 7, tile = idx >> 12;
        int n = tile * 16 + (l & 15);
        int k = kt * 32 + (l >> 4) * 8 + j;
        w1p[idx] = f2bf(W1[k * 512 + n]);
    } else if (idx < 393216) {               // W2: K=512 (kt 0..15), N=512 (tile 0..31)
        int i2 = idx - 131072;
        int j = i2 & 7, l = (i2 >> 3) & 63, kt = (i2 >> 9) & 15, tile = i2 >> 13;
        int n = tile * 16 + (l & 15);
        int k = kt * 32 + (l >> 4) * 8 + j;
        w2p[i2] = f2bf(W2[k * 512 + n]);
    } else if (idx < 524288) {               // W3: K=512 (kt 0..15), N=256 (tile 0..15)
        int i3 = idx - 393216;
        int j = i3 & 7, l = (i3 >> 3) & 63, kt = (i3 >> 9) & 15, tile = i3 >> 13;
        int n = tile * 16 + (l & 15);
        int k = kt * 32 + (l >> 4) * 8 + j;
        w3p[i3] = f2bf(W3[k * 256 + n]);
    }
}

// ---------------- K1: fused MLP chain — EDGE-INNER (R13) + cvt_pk (R15) + bf16-z (R17) ----------------
// 2048 blocks x 512 thr (8 waves), block owns 32 batch rows.
// All 3 edges per K-step share each B-fragment (24 MFMAs/step). Barriers: 4/pass.
// z written to d_out as bf16 in the first 512B of each row's 1KB fp32 slot
// (halves z write; k_norm re-expands in place). BN stats from fp32 pre-round.
// REGISTER MODEL (R16 lesson): arch-VGPR cap is 128 (VGPR_Count) even with
// waves_per_eu(2,2); accumulators live in AGPRs. R15's buffer set (A 2-slot 48
// + B 2-slot 32) is at the edge — do NOT add prefetch depth (R16: +16 regs ->
// 210 MB spills, +39% dur).
// LDS map (144 KB, 1 block/CU): h1s[e] e*32768 [0,96K); ebuf[e] 96K+e*16384;
// aggb = 96K (aliases dead ebuf after layer1); zbufB bf16 [32][256] at [0,16K).
// amdgpu_waves_per_eu(2,2) pins the allocator (R12 lesson).
__global__ __launch_bounds__(512) __attribute__((amdgpu_waves_per_eu(2, 2)))
void k_fused(const float* __restrict__ x,
             const unsigned short* __restrict__ w1p,
             const unsigned short* __restrict__ w2p,
             const unsigned short* __restrict__ w3p,
             const float* __restrict__ b1, const float* __restrict__ b2,
             const float* __restrict__ b3,
             float* __restrict__ out,
             float* __restrict__ psum, float* __restrict__ psumsq) {
    __shared__ __align__(16) unsigned char smem[147456];
    unsigned char* h1b  = smem;             // 3 x 32 KB
    unsigned char* ebb  = smem + 98304;     // 3 x 16 KB
    unsigned char* aggb = smem + 98304;     // 32 KB (aliases ebuf0+ebuf1)
    unsigned short* zbufB = (unsigned short*)smem;  // [32][256] bf16 (aliases h1s[0])

    const int tid = threadIdx.x;
    const int w   = tid >> 6;
    const int l   = tid & 63;
    const int l15 = l & 15;
    const int lg  = l >> 4;
    const int blk = blockIdx.x;
    const int row0 = blk * BM;

    const int sr  = tid & 31;
    const int skg = tid >> 5;
    const float* xrow = x + (size_t)(row0 + sr) * 768;

    float bias1[4], bias2[4];
#pragma unroll
    for (int nt = 0; nt < 4; ++nt) {
        bias1[nt] = b1[w * 64 + nt * 16 + l15];
        bias2[nt] = b2[w * 64 + nt * 16 + l15];
    }
    float bias3[2];
#pragma unroll
    for (int nt = 0; nt < 2; ++nt) bias3[nt] = b3[w * 32 + nt * 16 + l15];

    // ---- stage all 3 edge buffers (x loaded once per node) ----
#pragma unroll
    for (int h = 0; h < 2; ++h) {
        int kg = skg + h * 16;
        float4 n0a = *(const float4*)(xrow + kg * 8);
        float4 n0b = *(const float4*)(xrow + kg * 8 + 4);
        float4 n1a = *(const float4*)(xrow + 256 + kg * 8);
        float4 n1b = *(const float4*)(xrow + 256 + kg * 8 + 4);
        float4 n2a = *(const float4*)(xrow + 512 + kg * 8);
        float4 n2b = *(const float4*)(xrow + 512 + kg * 8 + 4);
        *(uint4*)(ebb + cellb(kg, sr))         = pack8(n0a, n0b, n1a, n1b);  // e01
        *(uint4*)(ebb + 16384 + cellb(kg, sr)) = pack8(n0a, n0b, n2a, n2b);  // e02
        *(uint4*)(ebb + 32768 + cellb(kg, sr)) = pack8(n1a, n1b, n2a, n2b);  // e12
    }

    // ---- layer1: c1[e] = e @ W1  (K=256, 8 kt, B shared across 3 edges) ----
    f32x4 c1[3][2][4];
#pragma unroll
    for (int e = 0; e < 3; ++e)
#pragma unroll
        for (int mt = 0; mt < 2; ++mt)
#pragma unroll
            for (int nt = 0; nt < 4; ++nt) c1[e][mt][nt] = (f32x4){0.f, 0.f, 0.f, 0.f};

    {
        short8 aP[3][2], aQ[3][2], bP[4], bQ[4];
#pragma unroll
        for (int nt = 0; nt < 4; ++nt)
            bP[nt] = *(const short8*)(w1p + (((w * 4 + nt) * 8) * 64 + l) * 8);
        __syncthreads();   // ebuf ready
#pragma unroll
        for (int e = 0; e < 3; ++e)
#pragma unroll
            for (int mt = 0; mt < 2; ++mt)
                aP[e][mt] = *(const short8*)(ebb + e * 16384 + cellb(lg, mt * 16 + l15));
#pragma unroll 1
        for (int kt = 0; kt < 8; kt += 2) {
#pragma unroll
            for (int e = 0; e < 3; ++e)
#pragma unroll
                for (int mt = 0; mt < 2; ++mt)
                    aQ[e][mt] = *(const short8*)(ebb + e * 16384 + cellb((kt + 1) * 4 + lg, mt * 16 + l15));
#pragma unroll
            for (int nt = 0; nt < 4; ++nt)
                bQ[nt] = *(const short8*)(w1p + (((w * 4 + nt) * 8 + kt + 1) * 64 + l) * 8);
            __builtin_amdgcn_s_setprio(1);
#pragma unroll
            for (int nt = 0; nt < 4; ++nt)
#pragma unroll
                for (int e = 0; e < 3; ++e)
#pragma unroll
                    for (int mt = 0; mt < 2; ++mt)
                        c1[e][mt][nt] = __builtin_amdgcn_mfma_f32_16x16x32_bf16(aP[e][mt], bP[nt], c1[e][mt][nt], 0, 0, 0);
            __builtin_amdgcn_s_setprio(0);
            if (kt + 2 < 8) {
#pragma unroll
                for (int e = 0; e < 3; ++e)
#pragma unroll
                    for (int mt = 0; mt < 2; ++mt)
                        aP[e][mt] = *(const short8*)(ebb + e * 16384 + cellb((kt + 2) * 4 + lg, mt * 16 + l15));
#pragma unroll
                for (int nt = 0; nt < 4; ++nt)
                    bP[nt] = *(const short8*)(w1p + (((w * 4 + nt) * 8 + kt + 2) * 64 + l) * 8);
            }
            __builtin_amdgcn_s_setprio(1);
#pragma unroll
            for (int nt = 0; nt < 4; ++nt)
#pragma unroll
                for (int e = 0; e < 3; ++e)
#pragma unroll
                    for (int mt = 0; mt < 2; ++mt)
                        c1[e][mt][nt] = __builtin_amdgcn_mfma_f32_16x16x32_bf16(aQ[e][mt], bQ[nt], c1[e][mt][nt], 0, 0, 0);
            __builtin_amdgcn_s_setprio(0);
        }
    }

    // ---- layer1 epilogue: relu(c1+b1) -> h1s[e] (cvt_pk pairs, u16 lo/hi stores) ----
#pragma unroll
    for (int e = 0; e < 3; ++e)
#pragma unroll
        for (int nt = 0; nt < 4; ++nt) {
            int c = w * 64 + nt * 16 + l15;
            int cb = ((c & 7) << 1);
            unsigned char* base = h1b + e * 32768;
#pragma unroll
            for (int mt = 0; mt < 2; ++mt) {
                int r0 = mt * 16 + lg * 4;
                float v0 = fmaxf(c1[e][mt][nt][0] + bias1[nt], 0.f);
                float v1 = fmaxf(c1[e][mt][nt][1] + bias1[nt], 0.f);
                float v2 = fmaxf(c1[e][mt][nt][2] + bias1[nt], 0.f);
                float v3 = fmaxf(c1[e][mt][nt][3] + bias1[nt], 0.f);
                unsigned p01 = cvtpk(v0, v1);
                unsigned p23 = cvtpk(v2, v3);
                *(unsigned short*)(base + cellb(c >> 3, r0 + 0) + cb) = (unsigned short)p01;
                *(unsigned short*)(base + cellb(c >> 3, r0 + 1) + cb) = (unsigned short)(p01 >> 16);
                *(unsigned short*)(base + cellb(c >> 3, r0 + 2) + cb) = (unsigned short)p23;
                *(unsigned short*)(base + cellb(c >> 3, r0 + 3) + cb) = (unsigned short)(p23 >> 16);
            }
        }
    __syncthreads();   // h1s ready; ebuf reads done (aggb overwrite safe later)

    // ---- layer2: c2[e] = h1[e] @ W2  (K=512, 16 kt, B shared across edges) ----
    f32x4 c2[3][2][4];
#pragma unroll
    for (int e = 0; e < 3; ++e)
#pragma unroll
        for (int mt = 0; mt < 2; ++mt)
#pragma unroll
            for (int nt = 0; nt < 4; ++nt) c2[e][mt][nt] = (f32x4){0.f, 0.f, 0.f, 0.f};

    {
        short8 aP[3][2], aQ[3][2], bP[4], bQ[4];
#pragma unroll
        for (int nt = 0; nt < 4; ++nt)
            bP[nt] = *(const short8*)(w2p + (((w * 4 + nt) * 16) * 64 + l) * 8);
#pragma unroll
        for (int e = 0; e < 3; ++e)
#pragma unroll
            for (int mt = 0; mt < 2; ++mt)
                aP[e][mt] = *(const short8*)(h1b + e * 32768 + cellb(lg, mt * 16 + l15));
#pragma unroll 1
        for (int kt = 0; kt < 16; kt += 2) {
#pragma unroll
            for (int e = 0; e < 3; ++e)
#pragma unroll
                for (int mt = 0; mt < 2; ++mt)
                    aQ[e][mt] = *(const short8*)(h1b + e * 32768 + cellb((kt + 1) * 4 + lg, mt * 16 + l15));
#pragma unroll
            for (int nt = 0; nt < 4; ++nt)
                bQ[nt] = *(const short8*)(w2p + (((w * 4 + nt) * 16 + kt + 1) * 64 + l) * 8);
            __builtin_amdgcn_s_setprio(1);
#pragma unroll
            for (int nt = 0; nt < 4; ++nt)
#pragma unroll
                for (int e = 0; e < 3; ++e)
#pragma unroll
                    for (int mt = 0; mt < 2; ++mt)
                        c2[e][mt][nt] = __builtin_amdgcn_mfma_f32_16x16x32_bf16(aP[e][mt], bP[nt], c2[e][mt][nt], 0, 0, 0);
            __builtin_amdgcn_s_setprio(0);
            if (kt + 2 < 16) {
#pragma unroll
                for (int e = 0; e < 3; ++e)
#pragma unroll
                    for (int mt = 0; mt < 2; ++mt)
                        aP[e][mt] = *(const short8*)(h1b + e * 32768 + cellb((kt + 2) * 4 + lg, mt * 16 + l15));
#pragma unroll
                for (int nt = 0; nt < 4; ++nt)
                    bP[nt] = *(const short8*)(w2p + (((w * 4 + nt) * 16 + kt + 2) * 64 + l) * 8);
            }
            __builtin_amdgcn_s_setprio(1);
#pragma unroll
            for (int nt = 0; nt < 4; ++nt)
#pragma unroll
                for (int e = 0; e < 3; ++e)
#pragma unroll
                    for (int mt = 0; mt < 2; ++mt)
                        c2[e][mt][nt] = __builtin_amdgcn_mfma_f32_16x16x32_bf16(aQ[e][mt], bQ[nt], c2[e][mt][nt], 0, 0, 0);
            __builtin_amdgcn_s_setprio(0);
        }
    }

    // ---- agg = sum_e relu(c2[e]+b2) -> aggb (cvt_pk pairs, u16 lo/hi stores) ----
#pragma unroll
    for (int nt = 0; nt < 4; ++nt) {
        int c = w * 64 + nt * 16 + l15;
        int cb = ((c & 7) << 1);
#pragma unroll
        for (int mt = 0; mt < 2; ++mt) {
            int r0 = mt * 16 + lg * 4;
            float s0 = 0.f, s1 = 0.f, s2 = 0.f, s3 = 0.f;
#pragma unroll
            for (int e = 0; e < 3; ++e) {
                s0 += fmaxf(c2[e][mt][nt][0] + bias2[nt], 0.f);
                s1 += fmaxf(c2[e][mt][nt][1] + bias2[nt], 0.f);
                s2 += fmaxf(c2[e][mt][nt][2] + bias2[nt], 0.f);
                s3 += fmaxf(c2[e][mt][nt][3] + bias2[nt], 0.f);
            }
            unsigned p01 = cvtpk(s0, s1);
            unsigned p23 = cvtpk(s2, s3);
            *(unsigned short*)(aggb + cellb(c >> 3, r0 + 0) + cb) = (unsigned short)p01;
            *(unsigned short*)(aggb + cellb(c >> 3, r0 + 1) + cb) = (unsigned short)(p01 >> 16);
            *(unsigned short*)(aggb + cellb(c >> 3, r0 + 2) + cb) = (unsigned short)p23;
            *(unsigned short*)(aggb + cellb(c >> 3, r0 + 3) + cb) = (unsigned short)(p23 >> 16);
        }
    }
    __syncthreads();   // aggb complete; h1s reads all done

    // ---- layer3: z = agg @ W3 + b3  (K=512, wave owns 32 cols, ping-pong) ----
    f32x4 c3[2][2];
#pragma unroll
    for (int mt = 0; mt < 2; ++mt)
#pragma unroll
        for (int nt = 0; nt < 2; ++nt) c3[mt][nt] = (f32x4){0.f, 0.f, 0.f, 0.f};

    {
        short8 aP[2], aQ[2], bP[2], bQ[2];
#pragma unroll
        for (int nt = 0; nt < 2; ++nt)
            bP[nt] = *(const short8*)(w3p + (((w * 2 + nt) * 16) * 64 + l) * 8);
#pragma unroll
        for (int mt = 0; mt < 2; ++mt)
            aP[mt] = *(const short8*)(aggb + cellb(lg, mt * 16 + l15));
#pragma unroll 1
        for (int kt = 0; kt < 16; kt += 2) {
#pragma unroll
            for (int mt = 0; mt < 2; ++mt)
                aQ[mt] = *(const short8*)(aggb + cellb((kt + 1) * 4 + lg, mt * 16 + l15));
#pragma unroll
            for (int nt = 0; nt < 2; ++nt)
                bQ[nt] = *(const short8*)(w3p + (((w * 2 + nt) * 16 + kt + 1) * 64 + l) * 8);
            __builtin_amdgcn_s_setprio(1);
#pragma unroll
            for (int nt = 0; nt < 2; ++nt)
#pragma unroll
                for (int mt = 0; mt < 2; ++mt)
                    c3[mt][nt] = __builtin_amdgcn_mfma_f32_16x16x32_bf16(aP[mt], bP[nt], c3[mt][nt], 0, 0, 0);
            __builtin_amdgcn_s_setprio(0);
            if (kt + 2 < 16) {
#pragma unroll
                for (int mt = 0; mt < 2; ++mt)
                    aP[mt] = *(const short8*)(aggb + cellb((kt + 2) * 4 + lg, mt * 16 + l15));
#pragma unroll
                for (int nt = 0; nt < 2; ++nt)
                    bP[nt] = *(const short8*)(w3p + (((w * 2 + nt) * 16 + kt + 2) * 64 + l) * 8);
            }
            __builtin_amdgcn_s_setprio(1);
#pragma unroll
            for (int nt = 0; nt < 2; ++nt)
#pragma unroll
                for (int mt = 0; mt < 2; ++mt)
                    c3[mt][nt] = __builtin_amdgcn_mfma_f32_16x16x32_bf16(aQ[mt], bQ[nt], c3[mt][nt], 0, 0, 0);
            __builtin_amdgcn_s_setprio(0);
        }
    }

    // ---- z epilogue: bf16 z -> zbufB (aliases h1s[0]) + BN partials (fp32) ----
#pragma unroll
    for (int nt = 0; nt < 2; ++nt) {
        int c = w * 32 + nt * 16 + l15;
        float s = 0.f, q = 0.f;
#pragma unroll
        for (int mt = 0; mt < 2; ++mt) {
            int r0 = mt * 16 + lg * 4;
            float v0 = c3[mt][nt][0] + bias3[nt];
            float v1 = c3[mt][nt][1] + bias3[nt];
            float v2 = c3[mt][nt][2] + bias3[nt];
            float v3 = c3[mt][nt][3] + bias3[nt];
            unsigned p01 = cvtpk(v0, v1);
            unsigned p23 = cvtpk(v2, v3);
            zbufB[(r0 + 0) * 256 + c] = (unsigned short)p01;
            zbufB[(r0 + 1) * 256 + c] = (unsigned short)(p01 >> 16);
            zbufB[(r0 + 2) * 256 + c] = (unsigned short)p23;
            zbufB[(r0 + 3) * 256 + c] = (unsigned short)(p23 >> 16);
            s += v0 + v1 + v2 + v3;
            q += v0 * v0 + v1 * v1 + v2 * v2 + v3 * v3;
        }
        s += __shfl_xor(s, 16); s += __shfl_xor(s, 32);
        q += __shfl_xor(q, 16); q += __shfl_xor(q, 32);
        if (lg == 0) {
            psum[c * NBLK + blk] = s;
            psumsq[c * NBLK + blk] = q;
        }
    }
    __syncthreads();
    {
        // bf16 z of global row r -> first 512 B of out's 1 KB fp32 row slot
        const uint4* zb = (const uint4*)zbufB;
        char* ob = (char*)out;
#pragma unroll
        for (int it = 0; it < 2; ++it) {
            int j = tid + it * 512;          // 0..1023 uint4 (16 KB)
            int r = j >> 5, i = j & 31;
            *(uint4*)(ob + (size_t)(row0 + r) * 1024 + i * 16) = zb[j];
        }
    }
}

// ---------------- K2: reduce 2048 partials -> scale/shift ----------------
__global__ void k_stats2(const float* __restrict__ psum, const float* __restrict__ psumsq,
                         const float* __restrict__ gamma, const float* __restrict__ beta,
                         float* __restrict__ scale, float* __restrict__ shift) {
    int f = blockIdx.x, t = threadIdx.x;
    const float* ps = psum + f * NBLK;
    const float* pq = psumsq + f * NBLK;
    float s = 0.f, q = 0.f;
#pragma unroll
    for (int i = 0; i < 8; ++i) {
        s += ps[t + i * 256];
        q += pq[t + i * 256];
    }
#pragma unroll
    for (int o = 32; o > 0; o >>= 1) {
        s += __shfl_down(s, o);
        q += __shfl_down(q, o);
    }
    __shared__ float ls[4], lq[4];
    if ((t & 63) == 0) { ls[t >> 6] = s; lq[t >> 6] = q; }
    __syncthreads();
    if (t == 0) {
        s = ls[0] + ls[1] + ls[2] + ls[3];
        q = lq[0] + lq[1] + lq[2] + lq[3];
        float mu  = s * (1.f / 65536.f);
        float var = q * (1.f / 65536.f) - mu * mu;
        float sc  = gamma[f] * rsqrtf(var + EPS);
        scale[f] = sc;
        shift[f] = beta[f] - mu * sc;
    }
}

// ---------------- K3: expand bf16 z in-place to normalized fp32 ----------------
// Block b owns rows [b*32, b*32+32) — reads its own bf16 region into registers,
// barrier (drains vmcnt), then overwrites the same slots as fp32. No cross-block
// overlap (disjoint 32-row slabs).
__global__ void k_norm(float* out, const float* __restrict__ scale,
                       const float* __restrict__ shift) {
    const int tid = threadIdx.x;
    const size_t row0 = (size_t)blockIdx.x * 32;
    const char* ob = (const char*)out;

    short8 zv[4];
    int rr[4], ii[4];
#pragma unroll
    for (int it = 0; it < 4; ++it) {
        int j = tid + it * 256;             // 0..1023: (row, 16B-chunk)
        rr[it] = j >> 5; ii[it] = j & 31;
        zv[it] = *(const short8*)(ob + (row0 + rr[it]) * 1024 + ii[it] * 16);
    }
    __syncthreads();   // all reads landed (vmcnt drained) before any overwrite

#pragma unroll
    for (int it = 0; it < 4; ++it) {
        int c0 = ii[it] * 8;
        float4 sc0 = *(const float4*)(scale + c0);
        float4 sc1 = *(const float4*)(scale + c0 + 4);
        float4 sh0 = *(const float4*)(shift + c0);
        float4 sh1 = *(const float4*)(shift + c0 + 4);
        float4 o0, o1;
        o0.x = bf2f((unsigned short)zv[it][0]) * sc0.x + sh0.x;
        o0.y = bf2f((unsigned short)zv[it][1]) * sc0.y + sh0.y;
        o0.z = bf2f((unsigned short)zv[it][2]) * sc0.z + sh0.z;
        o0.w = bf2f((unsigned short)zv[it][3]) * sc0.w + sh0.w;
        o1.x = bf2f((unsigned short)zv[it][4]) * sc1.x + sh1.x;
        o1.y = bf2f((unsigned short)zv[it][5]) * sc1.y + sh1.y;
        o1.z = bf2f((unsigned short)zv[it][6]) * sc1.z + sh1.z;
        o1.w = bf2f((unsigned short)zv[it][7]) * sc1.w + sh1.w;
        float* dst = out + (row0 + rr[it]) * 256 + c0;
        *(float4*)dst = o0;
        *(float4*)(dst + 4) = o1;
    }
}

extern "C" void kernel_launch(void* const* d_in, const int* in_sizes, int n_in,
                              void* d_out, int out_size, void* d_ws, size_t ws_size,
                              hipStream_t stream) {
    const float* x     = (const float*)d_in[0];
    const float* W1    = (const float*)d_in[1];
    const float* b1    = (const float*)d_in[2];
    const float* W2    = (const float*)d_in[3];
    const float* b2    = (const float*)d_in[4];
    const float* W3    = (const float*)d_in[5];
    const float* b3    = (const float*)d_in[6];
    const float* gamma = (const float*)d_in[7];
    const float* beta  = (const float*)d_in[8];

    char* ws = (char*)d_ws;
    unsigned short* w1p = (unsigned short*)(ws);            // 256 KB
    unsigned short* w2p = (unsigned short*)(ws + 262144);   // 512 KB
    unsigned short* w3p = (unsigned short*)(ws + 786432);   // 256 KB
    float* psum   = (float*)(ws + 1048576);                 // 2 MB
    float* psumsq = (float*)(ws + 3145728);                 // 2 MB
    float* scale  = (float*)(ws + 5242880);                 // 1 KB
    float* shift  = (float*)(ws + 5243904);                 // 1 KB

    float* out = (float*)d_out;

    k_prep<<<2048, 256, 0, stream>>>(W1, W2, W3, w1p, w2p, w3p);
    k_fused<<<NBLK, 512, 0, stream>>>(x, w1p, w2p, w3p, b1, b2, b3, out, psum, psumsq);
    k_stats2<<<256, 256, 0, stream>>>(psum, psumsq, gamma, beta, scale, shift);
    k_norm<<<2048, 256, 0, stream>>>(out, scale, shift);
}